// Round 11
// baseline (606.963 us; speedup 1.0000x reference)
//
#include <hip/hip_runtime.h>
#include <stdint.h>

typedef __attribute__((ext_vector_type(8))) short s8v;   // 8 bf16 = 4 VGPRs (MFMA A/B frag)
typedef __attribute__((ext_vector_type(4))) float f4v;   // MFMA C/D frag

constexpr int ECHUNK = 4096;   // edges per bucket-count/scatter block

// ---------------- Threefry-2x32 (exact JAX implementation) ----------------
__host__ __device__ inline uint32_t rotl32(uint32_t x, int r) {
    return (x << r) | (x >> (32 - r));
}

__host__ __device__ inline void tf2x32(uint32_t k0, uint32_t k1,
                                       uint32_t x0, uint32_t x1,
                                       uint32_t& o0, uint32_t& o1) {
    const uint32_t ks0 = k0, ks1 = k1, ks2 = k0 ^ k1 ^ 0x1BD11BDAu;
    x0 += ks0; x1 += ks1;
    x0 += x1; x1 = rotl32(x1, 13); x1 ^= x0;
    x0 += x1; x1 = rotl32(x1, 15); x1 ^= x0;
    x0 += x1; x1 = rotl32(x1, 26); x1 ^= x0;
    x0 += x1; x1 = rotl32(x1, 6);  x1 ^= x0;
    x0 += ks1; x1 += ks2 + 1u;
    x0 += x1; x1 = rotl32(x1, 17); x1 ^= x0;
    x0 += x1; x1 = rotl32(x1, 29); x1 ^= x0;
    x0 += x1; x1 = rotl32(x1, 16); x1 ^= x0;
    x0 += x1; x1 = rotl32(x1, 24); x1 ^= x0;
    x0 += ks2; x1 += ks0 + 2u;
    x0 += x1; x1 = rotl32(x1, 13); x1 ^= x0;
    x0 += x1; x1 = rotl32(x1, 15); x1 ^= x0;
    x0 += x1; x1 = rotl32(x1, 26); x1 ^= x0;
    x0 += x1; x1 = rotl32(x1, 6);  x1 ^= x0;
    x0 += ks0; x1 += ks1 + 3u;
    x0 += x1; x1 = rotl32(x1, 17); x1 ^= x0;
    x0 += x1; x1 = rotl32(x1, 29); x1 ^= x0;
    x0 += x1; x1 = rotl32(x1, 16); x1 ^= x0;
    x0 += x1; x1 = rotl32(x1, 24); x1 ^= x0;
    x0 += ks1; x1 += ks2 + 4u;
    x0 += x1; x1 = rotl32(x1, 13); x1 ^= x0;
    x0 += x1; x1 = rotl32(x1, 15); x1 ^= x0;
    x0 += x1; x1 = rotl32(x1, 26); x1 ^= x0;
    x0 += x1; x1 = rotl32(x1, 6);  x1 ^= x0;
    x0 += ks2; x1 += ks0 + 5u;
    o0 = x0; o1 = x1;
}

// ---------------- bf16 helpers ----------------
__device__ inline uint16_t f2bf(float f) {
    uint32_t u = __float_as_uint(f);
    return (uint16_t)((u + 0x7fffu + ((u >> 16) & 1u)) >> 16);   // RNE
}
__device__ inline float bflo(uint32_t v) { return __uint_as_float(v << 16); }
__device__ inline float bfhi(uint32_t v) { return __uint_as_float(v & 0xffff0000u); }

// ---------------- dropout mask precompute ----------------
// PARTITIONABLE threefry (modern JAX default): bits(idx) = o0^o1 of tf(key, 0, idx);
// keep <=> bits < 2^31. Word i holds keep-bits for elements [32i, 32i+32).
__global__ __launch_bounds__(256) void mask_kernel(
        uint32_t* __restrict__ mA, uint32_t* __restrict__ mB, int nwords,
        uint32_t a0, uint32_t a1, uint32_t b0, uint32_t b1) {
    int i = blockIdx.x * blockDim.x + threadIdx.x;
    if (i >= nwords) return;
    uint32_t base = (uint32_t)i << 5;
    uint32_t wa = 0, wb = 0;
#pragma unroll 4
    for (int b = 0; b < 32; ++b) {
        uint32_t o0, o1;
        tf2x32(a0, a1, 0u, base + (uint32_t)b, o0, o1);
        wa |= ((((o0 ^ o1) >> 31) ^ 1u)) << b;
        tf2x32(b0, b1, 0u, base + (uint32_t)b, o0, o1);
        wb |= ((((o0 ^ o1) >> 31) ^ 1u)) << b;
    }
    mA[i] = wa;
    mB[i] = wb;
}

// ---------------- edge_index dtype detection ----------------
__global__ void detect_kernel(const int* __restrict__ w, int* __restrict__ flag64) {
    __shared__ int s[256];
    int t = threadIdx.x;
    int acc = 0;
    for (int i = t; i < 2048; i += 256) acc |= w[2 * i + 1];
    s[t] = acc;
    __syncthreads();
    for (int off = 128; off > 0; off >>= 1) {
        if (t < off) s[t] |= s[t + off];
        __syncthreads();
    }
    if (t == 0) *flag64 = (s[0] == 0) ? 1 : 0;
}

__device__ inline int edge_src(const int* w, int e, int f64) {
    return f64 ? w[2 * e] : w[e];
}
__device__ inline int edge_dst(const int* w, int e, int E, int f64) {
    return f64 ? w[2 * E + 2 * e] : w[E + e];
}

// ---------------- bucketed CSR construction ----------------
// Buckets of 512 node ids (bucket = dst >> 9). tmp entry packs src (17b, N<2^17)
// and dst-offset-within-bucket (9b): v = src | (doff << 17).
__global__ __launch_bounds__(256) void bucketcount_kernel(
        const int* __restrict__ w, const int* __restrict__ flag64,
        int* __restrict__ hist, int E, int nA, int NBUK) {
    __shared__ int cnt[256];
    int t = threadIdx.x;
    if (t < NBUK) cnt[t] = 0;
    __syncthreads();
    int f64 = *flag64;
    int lo = blockIdx.x * ECHUNK, hi = min(E, lo + ECHUNK);
    for (int e = lo + t; e < hi; e += 256)
        atomicAdd(&cnt[edge_dst(w, e, E, f64) >> 9], 1);
    __syncthreads();
    if (t < NBUK) hist[t * nA + blockIdx.x] = cnt[t];
}

__global__ void scan1_kernel(const int* __restrict__ in, int* __restrict__ out,
                             int* __restrict__ bsum, int n) {
    __shared__ int s[512];
    int t = threadIdx.x;
    int i = blockIdx.x * 512 + t;
    int v = (i < n) ? in[i] : 0;
    s[t] = v;
    __syncthreads();
    for (int off = 1; off < 512; off <<= 1) {
        int x = (t >= off) ? s[t - off] : 0;
        __syncthreads();
        s[t] += x;
        __syncthreads();
    }
    if (i < n) out[i + 1] = s[t];
    if (t == 511) bsum[blockIdx.x] = s[511];
}

__global__ void scan2_kernel(int* __restrict__ bsum, int nb) {
    if (threadIdx.x == 0 && blockIdx.x == 0) {
        int run = 0;
        for (int b = 0; b < nb; ++b) { int tmp = bsum[b]; bsum[b] = run; run += tmp; }
    }
}

__global__ void scan3_kernel(int* __restrict__ out, const int* __restrict__ bsum, int n) {
    int i = blockIdx.x * 512 + threadIdx.x;
    if (i < n) out[i + 1] += bsum[blockIdx.x];
    if (i == 0) out[0] = 0;
}

__global__ __launch_bounds__(256) void bucketscatter_kernel(
        const int* __restrict__ w, const int* __restrict__ flag64,
        const int* __restrict__ bofs, uint32_t* __restrict__ tmp, int E, int nA, int NBUK) {
    __shared__ int sbase[256];
    int t = threadIdx.x;
    if (t < NBUK) sbase[t] = bofs[t * nA + blockIdx.x];
    __syncthreads();
    int f64 = *flag64;
    int lo = blockIdx.x * ECHUNK, hi = min(E, lo + ECHUNK);
    for (int e = lo + t; e < hi; e += 256) {
        int s = edge_src(w, e, f64);
        int d = edge_dst(w, e, E, f64);
        int p = atomicAdd(&sbase[d >> 9], 1);
        tmp[p] = (uint32_t)s | ((uint32_t)(d & 511) << 17);
    }
}

__global__ __launch_bounds__(256) void bucketdeg_kernel(
        const uint32_t* __restrict__ tmp, const int* __restrict__ bofs,
        int* __restrict__ deg, int nA, int N) {
    __shared__ int cnt[512];
    int b = blockIdx.x;
    int node0 = b << 9;
    int nn = min(512, N - node0);
    int t = threadIdx.x;
    for (int i = t; i < nn; i += 256) cnt[i] = 0;
    __syncthreads();
    int lo = bofs[b * nA], hi = bofs[(b + 1) * nA];
    for (int e = lo + t; e < hi; e += 256)
        atomicAdd(&cnt[tmp[e] >> 17], 1);
    __syncthreads();
    for (int i = t; i < nn; i += 256) deg[node0 + i] = cnt[i];
}

__global__ __launch_bounds__(256) void finescatter_kernel(
        const uint32_t* __restrict__ tmp, const int* __restrict__ bofs,
        const int* __restrict__ rowptr, int* __restrict__ col, int nA, int N) {
    __shared__ int cur[512];
    int b = blockIdx.x;
    int node0 = b << 9;
    int nn = min(512, N - node0);
    int t = threadIdx.x;
    for (int i = t; i < nn; i += 256) cur[i] = rowptr[node0 + i];
    __syncthreads();
    int lo = bofs[b * nA], hi = bofs[(b + 1) * nA];
    for (int e = lo + t; e < hi; e += 256) {
        uint32_t p = tmp[e];
        int q = atomicAdd(&cur[p >> 17], 1);
        col[q] = (int)(p & 0x1FFFFu);
    }
}

// ---------------- fp32 -> bf16 converts ----------------
__global__ void convx_kernel(const float* __restrict__ in, uint16_t* __restrict__ out, int n4) {
    int i = blockIdx.x * blockDim.x + threadIdx.x;
    if (i >= n4) return;
    float4 v = *(const float4*)(in + (size_t)i * 4);
    uint16_t o[4] = { f2bf(v.x), f2bf(v.y), f2bf(v.z), f2bf(v.w) };
    *(uint2*)(out + (size_t)i * 4) = *(uint2*)o;
}

// fused transpose+convert of all 6 weights: W [128][n] fp32 -> Wt [n][128] bf16
struct WPack {
    const float* src[6];
    uint16_t*    dst[6];
    int          n[6];
};
__global__ void convw_all_kernel(WPack p) {
    int s = blockIdx.y;
    int i = blockIdx.x * blockDim.x + threadIdx.x;   // i = n*128 + k
    int total = p.n[s] * 128;
    if (i >= total) return;
    int nn = i >> 7, k = i & 127;
    p.dst[s][i] = f2bf(p.src[s][(size_t)k * p.n[s] + nn]);
}

// ---------------- paired MFMA GEMM ----------------
// YL[M][N](bf16) = X@Wl ; ZB[M][N](bf16) = X@Wr + b.  X bf16 [M][128], Wt* bf16 [N][128].
__global__ __launch_bounds__(256) void pair_gemm_kernel(
        const uint16_t* __restrict__ Xb, const uint16_t* __restrict__ WtL,
        const uint16_t* __restrict__ WtR, const float* __restrict__ bias,
        uint16_t* __restrict__ YL, uint16_t* __restrict__ ZB, int M, int N) {
    const int l   = threadIdx.x & 63;
    const int wv  = threadIdx.x >> 6;
    const int row0 = blockIdx.x * 64 + wv * 16;
    const int ml  = l & 15;
    const int kg  = l >> 4;

    int arow = row0 + ml; if (arow >= M) arow = M - 1;
    const uint16_t* xr = Xb + (size_t)arow * 128 + kg * 8;
    s8v a0 = *(const s8v*)(xr);
    s8v a1 = *(const s8v*)(xr + 32);
    s8v a2 = *(const s8v*)(xr + 64);
    s8v a3 = *(const s8v*)(xr + 96);

    const int drow = row0 + kg * 4;

    for (int n0 = 0; n0 < N; n0 += 16) {
        const uint16_t* wl = WtL + (size_t)(n0 + ml) * 128 + kg * 8;
        const uint16_t* wr = WtR + (size_t)(n0 + ml) * 128 + kg * 8;
        f4v accL = {0.f, 0.f, 0.f, 0.f};
        f4v accR = {0.f, 0.f, 0.f, 0.f};
        accL = __builtin_amdgcn_mfma_f32_16x16x32_bf16(a0, *(const s8v*)(wl), accL, 0, 0, 0);
        accR = __builtin_amdgcn_mfma_f32_16x16x32_bf16(a0, *(const s8v*)(wr), accR, 0, 0, 0);
        accL = __builtin_amdgcn_mfma_f32_16x16x32_bf16(a1, *(const s8v*)(wl + 32), accL, 0, 0, 0);
        accR = __builtin_amdgcn_mfma_f32_16x16x32_bf16(a1, *(const s8v*)(wr + 32), accR, 0, 0, 0);
        accL = __builtin_amdgcn_mfma_f32_16x16x32_bf16(a2, *(const s8v*)(wl + 64), accL, 0, 0, 0);
        accR = __builtin_amdgcn_mfma_f32_16x16x32_bf16(a2, *(const s8v*)(wr + 64), accR, 0, 0, 0);
        accL = __builtin_amdgcn_mfma_f32_16x16x32_bf16(a3, *(const s8v*)(wl + 96), accL, 0, 0, 0);
        accR = __builtin_amdgcn_mfma_f32_16x16x32_bf16(a3, *(const s8v*)(wr + 96), accR, 0, 0, 0);

        float bv = bias[n0 + ml];
#pragma unroll
        for (int r = 0; r < 4; ++r) {
            int g = drow + r;
            if (g < M) {
                YL[(size_t)g * N + n0 + ml] = f2bf(accL[r]);
                ZB[(size_t)g * N + n0 + ml] = f2bf(accR[r] + bv);
            }
        }
    }
}

// ---------------- aggregation epilogues ----------------
// 2 nodes per wave; 32 lanes/node; lane owns 4 channels (uint2 = 4 bf16 = 8B load).
// mean + Z + relu + precomputed-dropout -> H bf16.
__global__ __launch_bounds__(256) void agg128_kernel(
        const uint16_t* __restrict__ Yl, const uint16_t* __restrict__ Zb,
        const int* __restrict__ rowptr, const int* __restrict__ col,
        const uint32_t* __restrict__ mask, uint16_t* __restrict__ H, int n) {
    int wv = threadIdx.x >> 6, lane = threadIdx.x & 63;
    int half = lane >> 5, sl = lane & 31;
    int node = blockIdx.x * 8 + wv * 2 + half;
    if (node >= n) return;
    const uint2* ylp = (const uint2*)Yl;
    int beg = rowptr[node], end = rowptr[node + 1];
    float a0 = 0.f, a1 = 0.f, a2 = 0.f, a3 = 0.f;
    int e = beg;
    for (; e + 3 < end; e += 4) {
        int j0 = col[e], j1 = col[e + 1], j2 = col[e + 2], j3 = col[e + 3];
        uint2 v0 = ylp[(size_t)j0 * 32 + sl];
        uint2 v1 = ylp[(size_t)j1 * 32 + sl];
        uint2 v2 = ylp[(size_t)j2 * 32 + sl];
        uint2 v3 = ylp[(size_t)j3 * 32 + sl];
        a0 += bflo(v0.x) + bflo(v1.x) + bflo(v2.x) + bflo(v3.x);
        a1 += bfhi(v0.x) + bfhi(v1.x) + bfhi(v2.x) + bfhi(v3.x);
        a2 += bflo(v0.y) + bflo(v1.y) + bflo(v2.y) + bflo(v3.y);
        a3 += bfhi(v0.y) + bfhi(v1.y) + bfhi(v2.y) + bfhi(v3.y);
    }
    for (; e < end; ++e) {
        uint2 v = ylp[(size_t)col[e] * 32 + sl];
        a0 += bflo(v.x); a1 += bfhi(v.x);
        a2 += bflo(v.y); a3 += bfhi(v.y);
    }
    int cnt = end - beg;
    float inv = 1.0f / (float)(cnt > 1 ? cnt : 1);
    uint2 z = ((const uint2*)Zb)[(size_t)node * 32 + sl];
    float h0 = fmaxf(a0 * inv + bflo(z.x), 0.0f);
    float h1 = fmaxf(a1 * inv + bfhi(z.x), 0.0f);
    float h2 = fmaxf(a2 * inv + bflo(z.y), 0.0f);
    float h3 = fmaxf(a3 * inv + bfhi(z.y), 0.0f);
    // keep bits for elements node*128 + sl*4 + {0..3}
    uint32_t mw  = mask[(size_t)node * 4 + (sl >> 3)];
    uint32_t nib = (mw >> ((sl & 7) * 4)) & 0xFu;
    h0 = (nib & 1u) ? h0 * 2.0f : 0.0f;
    h1 = (nib & 2u) ? h1 * 2.0f : 0.0f;
    h2 = (nib & 4u) ? h2 * 2.0f : 0.0f;
    h3 = (nib & 8u) ? h3 * 2.0f : 0.0f;
    uint2 o;
    o.x = (uint32_t)f2bf(h0) | ((uint32_t)f2bf(h1) << 16);
    o.y = (uint32_t)f2bf(h2) | ((uint32_t)f2bf(h3) << 16);
    ((uint2*)H)[(size_t)node * 32 + sl] = o;
}

// final layer: 2 nodes/wave, 32 lanes/node, lane owns 2 channels. mean + Z -> fp32 out.
__global__ __launch_bounds__(256) void agg64_kernel(
        const uint16_t* __restrict__ Yl, const uint16_t* __restrict__ Zb,
        const int* __restrict__ rowptr, const int* __restrict__ col,
        float* __restrict__ out, int n) {
    int wv = threadIdx.x >> 6, lane = threadIdx.x & 63;
    int half = lane >> 5, sl = lane & 31;
    int node = blockIdx.x * 8 + wv * 2 + half;
    if (node >= n) return;
    const uint32_t* ylp = (const uint32_t*)Yl;
    int beg = rowptr[node], end = rowptr[node + 1];
    float a0 = 0.f, a1 = 0.f;
    int e = beg;
    for (; e + 3 < end; e += 4) {
        int j0 = col[e], j1 = col[e + 1], j2 = col[e + 2], j3 = col[e + 3];
        uint32_t v0 = ylp[(size_t)j0 * 32 + sl];
        uint32_t v1 = ylp[(size_t)j1 * 32 + sl];
        uint32_t v2 = ylp[(size_t)j2 * 32 + sl];
        uint32_t v3 = ylp[(size_t)j3 * 32 + sl];
        a0 += bflo(v0) + bflo(v1) + bflo(v2) + bflo(v3);
        a1 += bfhi(v0) + bfhi(v1) + bfhi(v2) + bfhi(v3);
    }
    for (; e < end; ++e) {
        uint32_t v = ylp[(size_t)col[e] * 32 + sl];
        a0 += bflo(v); a1 += bfhi(v);
    }
    int cnt = end - beg;
    float inv = 1.0f / (float)(cnt > 1 ? cnt : 1);
    uint32_t z = ((const uint32_t*)Zb)[(size_t)node * 32 + sl];
    float2 o;
    o.x = a0 * inv + bflo(z);
    o.y = a1 * inv + bfhi(z);
    *(float2*)(out + (size_t)node * 64 + sl * 2) = o;
}

// ---------------- host ----------------
extern "C" void kernel_launch(void* const* d_in, const int* in_sizes, int n_in,
                              void* d_out, int out_size, void* d_ws, size_t ws_size,
                              hipStream_t stream) {
    const float* x   = (const float*)d_in[0];
    const int*   ei  = (const int*)d_in[1];
    const float* Wl0 = (const float*)d_in[2];
    const float* Wr0 = (const float*)d_in[3];
    const float* b0  = (const float*)d_in[4];
    const float* Wl1 = (const float*)d_in[5];
    const float* Wr1 = (const float*)d_in[6];
    const float* b1  = (const float*)d_in[7];
    const float* Wl2 = (const float*)d_in[8];
    const float* Wr2 = (const float*)d_in[9];
    const float* b2  = (const float*)d_in[10];

    const int N = in_sizes[0] / 128;     // 100000 (< 2^17, required by tmp packing)
    const int E = in_sizes[1] / 2;       // 1600000
    const int* srcp = ei;

    const int nA   = (E + ECHUNK - 1) / ECHUNK;
    const int NBUK = (N + 511) >> 9;
    const int L    = NBUK * nA;

    char* ws = (char*)d_ws;
    size_t off = 0;
    auto alloc = [&](size_t bytes) {
        size_t o = off;
        off = (off + bytes + 255) & ~(size_t)255;
        return o;
    };
    int*      rowptr = (int*)(ws + alloc((size_t)(N + 1) * 4));
    int*      deg    = (int*)(ws + alloc((size_t)N * 4));
    int*      bsum   = (int*)(ws + alloc(1024 * 4));
    int*      flag64 = (int*)(ws + alloc(256));
    int*      hist   = (int*)(ws + alloc((size_t)L * 4));
    int*      bofs   = (int*)(ws + alloc((size_t)(L + 1) * 4));
    uint32_t* tmp    = (uint32_t*)(ws + alloc((size_t)E * 4));
    int*      col    = (int*)(ws + alloc((size_t)E * 4));
    uint32_t* maskA  = (uint32_t*)(ws + alloc((size_t)N * 16));
    uint32_t* maskB  = (uint32_t*)(ws + alloc((size_t)N * 16));
    uint16_t* Xb     = (uint16_t*)(ws + alloc((size_t)N * 128 * 2));
    uint16_t* Hb     = (uint16_t*)(ws + alloc((size_t)N * 128 * 2));
    uint16_t* Byl    = (uint16_t*)(ws + alloc((size_t)N * 128 * 2));
    uint16_t* Czb    = (uint16_t*)(ws + alloc((size_t)N * 128 * 2));
    uint16_t* Wt0l   = (uint16_t*)(ws + alloc(128 * 128 * 2));
    uint16_t* Wt0r   = (uint16_t*)(ws + alloc(128 * 128 * 2));
    uint16_t* Wt1l   = (uint16_t*)(ws + alloc(128 * 128 * 2));
    uint16_t* Wt1r   = (uint16_t*)(ws + alloc(128 * 128 * 2));
    uint16_t* Wt2l   = (uint16_t*)(ws + alloc(128 * 128 * 2));
    uint16_t* Wt2r   = (uint16_t*)(ws + alloc(128 * 128 * 2));

    // dropout keys: jax.random.split(jax.random.key(42), 2), partitionable scheme.
    uint32_t k00, k01, k10, k11;
    tf2x32(0u, 42u, 0u, 0u, k00, k01);   // dk[0]
    tf2x32(0u, 42u, 0u, 1u, k10, k11);   // dk[1]

    // ---- dropout masks (dense-VALU, both layers) ----
    int nwords = N * 4;   // N*128/32
    mask_kernel<<<(nwords + 255) / 256, 256, 0, stream>>>(maskA, maskB, nwords,
                                                          k00, k01, k10, k11);

    // ---- bucketed CSR build ----
    detect_kernel<<<1, 256, 0, stream>>>(srcp, flag64);
    bucketcount_kernel<<<nA, 256, 0, stream>>>(srcp, flag64, hist, E, nA, NBUK);
    int NBL = (L + 511) / 512;
    scan1_kernel<<<NBL, 512, 0, stream>>>(hist, bofs, bsum, L);
    scan2_kernel<<<1, 64, 0, stream>>>(bsum, NBL);
    scan3_kernel<<<NBL, 512, 0, stream>>>(bofs, bsum, L);
    bucketscatter_kernel<<<nA, 256, 0, stream>>>(srcp, flag64, bofs, tmp, E, nA, NBUK);
    bucketdeg_kernel<<<NBUK, 256, 0, stream>>>(tmp, bofs, deg, nA, N);
    int NBN = (N + 511) / 512;
    scan1_kernel<<<NBN, 512, 0, stream>>>(deg, rowptr, bsum, N);
    scan2_kernel<<<1, 64, 0, stream>>>(bsum, NBN);
    scan3_kernel<<<NBN, 512, 0, stream>>>(rowptr, bsum, N);
    finescatter_kernel<<<NBUK, 256, 0, stream>>>(tmp, bofs, rowptr, col, nA, N);

    // ---- converts ----
    convx_kernel<<<(N * 128 / 4 + 255) / 256, 256, 0, stream>>>(x, Xb, N * 128 / 4);
    WPack wp;
    wp.src[0] = Wl0; wp.dst[0] = Wt0l; wp.n[0] = 128;
    wp.src[1] = Wr0; wp.dst[1] = Wt0r; wp.n[1] = 128;
    wp.src[2] = Wl1; wp.dst[2] = Wt1l; wp.n[2] = 128;
    wp.src[3] = Wr1; wp.dst[3] = Wt1r; wp.n[3] = 128;
    wp.src[4] = Wl2; wp.dst[4] = Wt2l; wp.n[4] = 64;
    wp.src[5] = Wr2; wp.dst[5] = Wt2r; wp.n[5] = 64;
    convw_all_kernel<<<dim3(64, 6), 256, 0, stream>>>(wp);

    dim3 blk(256);
    dim3 gg((N + 63) / 64);
    dim3 gagg((N + 7) / 8);

    // ---- layer 0 ----
    pair_gemm_kernel<<<gg, blk, 0, stream>>>(Xb, Wt0l, Wt0r, b0, Byl, Czb, N, 128);
    agg128_kernel<<<gagg, blk, 0, stream>>>(Byl, Czb, rowptr, col, maskA, Hb, N);
    // ---- layer 1 ----
    pair_gemm_kernel<<<gg, blk, 0, stream>>>(Hb, Wt1l, Wt1r, b1, Byl, Czb, N, 128);
    agg128_kernel<<<gagg, blk, 0, stream>>>(Byl, Czb, rowptr, col, maskB, Hb, N);
    // ---- layer 2: project (128->64) then aggregate ----
    pair_gemm_kernel<<<gg, blk, 0, stream>>>(Hb, Wt2l, Wt2r, b2, Byl, Czb, N, 64);
    agg64_kernel<<<gagg, blk, 0, stream>>>(Byl, Czb, rowptr, col, (float*)d_out, N);
}

// Round 12
// 557.931 us; speedup vs baseline: 1.0879x; 1.0879x over previous
//
#include <hip/hip_runtime.h>
#include <stdint.h>

typedef __attribute__((ext_vector_type(8))) short s8v;   // 8 bf16 = 4 VGPRs (MFMA A/B frag)
typedef __attribute__((ext_vector_type(4))) float f4v;   // MFMA C/D frag

constexpr int ECHUNK = 16384;  // edges per bucket-count/scatter block

// ---------------- Threefry-2x32 (exact JAX implementation) ----------------
__host__ __device__ inline uint32_t rotl32(uint32_t x, int r) {
    return (x << r) | (x >> (32 - r));
}

__host__ __device__ inline void tf2x32(uint32_t k0, uint32_t k1,
                                       uint32_t x0, uint32_t x1,
                                       uint32_t& o0, uint32_t& o1) {
    const uint32_t ks0 = k0, ks1 = k1, ks2 = k0 ^ k1 ^ 0x1BD11BDAu;
    x0 += ks0; x1 += ks1;
    x0 += x1; x1 = rotl32(x1, 13); x1 ^= x0;
    x0 += x1; x1 = rotl32(x1, 15); x1 ^= x0;
    x0 += x1; x1 = rotl32(x1, 26); x1 ^= x0;
    x0 += x1; x1 = rotl32(x1, 6);  x1 ^= x0;
    x0 += ks1; x1 += ks2 + 1u;
    x0 += x1; x1 = rotl32(x1, 17); x1 ^= x0;
    x0 += x1; x1 = rotl32(x1, 29); x1 ^= x0;
    x0 += x1; x1 = rotl32(x1, 16); x1 ^= x0;
    x0 += x1; x1 = rotl32(x1, 24); x1 ^= x0;
    x0 += ks2; x1 += ks0 + 2u;
    x0 += x1; x1 = rotl32(x1, 13); x1 ^= x0;
    x0 += x1; x1 = rotl32(x1, 15); x1 ^= x0;
    x0 += x1; x1 = rotl32(x1, 26); x1 ^= x0;
    x0 += x1; x1 = rotl32(x1, 6);  x1 ^= x0;
    x0 += ks0; x1 += ks1 + 3u;
    x0 += x1; x1 = rotl32(x1, 17); x1 ^= x0;
    x0 += x1; x1 = rotl32(x1, 29); x1 ^= x0;
    x0 += x1; x1 = rotl32(x1, 16); x1 ^= x0;
    x0 += x1; x1 = rotl32(x1, 24); x1 ^= x0;
    x0 += ks1; x1 += ks2 + 4u;
    x0 += x1; x1 = rotl32(x1, 13); x1 ^= x0;
    x0 += x1; x1 = rotl32(x1, 15); x1 ^= x0;
    x0 += x1; x1 = rotl32(x1, 26); x1 ^= x0;
    x0 += x1; x1 = rotl32(x1, 6);  x1 ^= x0;
    x0 += ks2; x1 += ks0 + 5u;
    o0 = x0; o1 = x1;
}

// PARTITIONABLE threefry dropout: bits = o0^o1 of tf(key, 0, idx); keep <=> bits < 2^31.
__device__ inline bool tf_keep(uint32_t idx, uint32_t k0, uint32_t k1) {
    uint32_t o0, o1;
    tf2x32(k0, k1, 0u, idx, o0, o1);
    return ((o0 ^ o1) >> 31) == 0u;
}

// ---------------- bf16 helpers ----------------
__device__ inline uint16_t f2bf(float f) {
    uint32_t u = __float_as_uint(f);
    return (uint16_t)((u + 0x7fffu + ((u >> 16) & 1u)) >> 16);   // RNE
}
__device__ inline float bflo(uint32_t v) { return __uint_as_float(v << 16); }
__device__ inline float bfhi(uint32_t v) { return __uint_as_float(v & 0xffff0000u); }

// per-block edge-dtype detect (int64 -> odd words of first 2048 entries all zero)
__device__ inline int block_detect64(const int* __restrict__ w, int* sf) {
    int t = threadIdx.x;
    if (t == 0) *sf = 0;
    __syncthreads();
    int acc = 0;
    for (int i = t; i < 2048; i += blockDim.x) acc |= w[2 * i + 1];
    if (acc) atomicOr(sf, 1);
    __syncthreads();
    return (*sf == 0) ? 1 : 0;
}

__device__ inline int edge_src(const int* w, int e, int f64) {
    return f64 ? w[2 * e] : w[e];
}
__device__ inline int edge_dst(const int* w, int e, int E, int f64) {
    return f64 ? w[2 * E + 2 * e] : w[E + e];
}

// ---------------- bucketed CSR construction ----------------
// Buckets of 512 node ids (bucket = dst >> 9). tmp packs src (17b, N<2^17) and
// dst-offset-in-bucket (9b): v = src | (doff << 17).

// Phase A: per-block LDS bucket histogram (+ inline dtype detect).
__global__ __launch_bounds__(256) void bucketcount_kernel(
        const int* __restrict__ w, int* __restrict__ hist, int E, int nA, int NBUK) {
    __shared__ int cnt[256];
    __shared__ int sf;
    int t = threadIdx.x;
    if (t < NBUK) cnt[t] = 0;
    int f64 = block_detect64(w, &sf);   // includes syncthreads
    int lo = blockIdx.x * ECHUNK, hi = min(E, lo + ECHUNK);
    for (int e = lo + t; e < hi; e += 256)
        atomicAdd(&cnt[edge_dst(w, e, E, f64) >> 9], 1);
    __syncthreads();
    if (t < NBUK) hist[t * nA + blockIdx.x] = cnt[t];
}

// Phase B: single-block exclusive scan of hist[0..L) -> bofs[0..L].
__global__ __launch_bounds__(1024) void scanL_kernel(
        const int* __restrict__ in, int* __restrict__ out, int n) {
    __shared__ int s[1024];
    int t = threadIdx.x;
    int elpt = (n + 1023) >> 10;
    int lo = t * elpt, hi = min(n, lo + elpt);
    int sum = 0;
    for (int i = lo; i < hi; ++i) sum += in[i];
    s[t] = sum;
    __syncthreads();
    for (int off = 1; off < 1024; off <<= 1) {
        int x = (t >= off) ? s[t - off] : 0;
        __syncthreads();
        s[t] += x;
        __syncthreads();
    }
    int run = s[t] - sum;   // exclusive prefix of this thread's chunk
    for (int i = lo; i < hi; ++i) { run += in[i]; out[i + 1] = run; }
    if (t == 0) out[0] = 0;
}

// Phase C: scatter packed edges into bucket-major segments (+ inline detect).
__global__ __launch_bounds__(256) void bucketscatter_kernel(
        const int* __restrict__ w, const int* __restrict__ bofs,
        uint32_t* __restrict__ tmp, int E, int nA, int NBUK) {
    __shared__ int sbase[256];
    __shared__ int sf;
    int t = threadIdx.x;
    if (t < NBUK) sbase[t] = bofs[t * nA + blockIdx.x];
    int f64 = block_detect64(w, &sf);
    int lo = blockIdx.x * ECHUNK, hi = min(E, lo + ECHUNK);
    for (int e = lo + t; e < hi; e += 256) {
        int s = edge_src(w, e, f64);
        int d = edge_dst(w, e, E, f64);
        int p = atomicAdd(&sbase[d >> 9], 1);
        tmp[p] = (uint32_t)s | ((uint32_t)(d & 511) << 17);
    }
}

// Phase D (fused): per-bucket deg-count + LDS scan + rowptr write + fine scatter.
__global__ __launch_bounds__(512) void fusedcsr_kernel(
        const uint32_t* __restrict__ tmp, const int* __restrict__ bofs,
        int* __restrict__ rowptr, int* __restrict__ col, int nA, int N, int E) {
    __shared__ int cnt[512];
    int b = blockIdx.x, t = threadIdx.x;
    int node0 = b << 9;
    int nn = min(512, N - node0);
    cnt[t] = 0;
    __syncthreads();
    int lo = bofs[b * nA], hi = bofs[(b + 1) * nA];
    for (int e = lo + t; e < hi; e += 512)
        atomicAdd(&cnt[tmp[e] >> 17], 1);
    __syncthreads();
    int v = cnt[t];
    for (int off = 1; off < 512; off <<= 1) {   // inclusive scan
        int x = (t >= off) ? cnt[t - off] : 0;
        __syncthreads();
        cnt[t] += x;
        __syncthreads();
    }
    int base = lo + (cnt[t] - v);   // bucket base + exclusive prefix
    if (t < nn) rowptr[node0 + t] = base;
    if (b == 0 && t == 0) rowptr[N] = E;
    __syncthreads();
    cnt[t] = base;                  // becomes the cursor
    __syncthreads();
    for (int e = lo + t; e < hi; e += 512) {
        uint32_t p = tmp[e];
        int q = atomicAdd(&cnt[p >> 17], 1);
        col[q] = (int)(p & 0x1FFFFu);
    }
}

// ---------------- fused fp32->bf16 converts (X + all 6 weights) ----------------
struct CPack {
    const float* wsrc[6];
    uint16_t*    wdst[6];
    int          wn[6];
    int          wboff[7];   // cumulative block offsets per weight section
};
__global__ void conv_all_kernel(const float* __restrict__ x, uint16_t* __restrict__ xb,
                                int nxb, CPack p) {
    int blk = blockIdx.x;
    if (blk < nxb) {
        int i = blk * 256 + threadIdx.x;          // group of 4 floats
        float4 v = *(const float4*)(x + (size_t)i * 4);
        uint16_t o[4] = { f2bf(v.x), f2bf(v.y), f2bf(v.z), f2bf(v.w) };
        *(uint2*)(xb + (size_t)i * 4) = *(uint2*)o;
    } else {
        int wb = blk - nxb;
        int s = 0;
        while (s < 5 && wb >= p.wboff[s + 1]) ++s;
        int i = (wb - p.wboff[s]) * 256 + threadIdx.x;   // i = n*128 + k
        int total = p.wn[s] * 128;
        if (i < total) {
            int nn = i >> 7, k = i & 127;
            p.wdst[s][i] = f2bf(p.wsrc[s][(size_t)k * p.wn[s] + nn]);
        }
    }
}

// ---------------- paired MFMA GEMM ----------------
// YL[M][N](bf16) = X@Wl ; ZB[M][N](bf16) = X@Wr + b.  X bf16 [M][128], Wt* bf16 [N][128].
__global__ __launch_bounds__(256) void pair_gemm_kernel(
        const uint16_t* __restrict__ Xb, const uint16_t* __restrict__ WtL,
        const uint16_t* __restrict__ WtR, const float* __restrict__ bias,
        uint16_t* __restrict__ YL, uint16_t* __restrict__ ZB, int M, int N) {
    const int l   = threadIdx.x & 63;
    const int wv  = threadIdx.x >> 6;
    const int row0 = blockIdx.x * 64 + wv * 16;
    const int ml  = l & 15;
    const int kg  = l >> 4;

    int arow = row0 + ml; if (arow >= M) arow = M - 1;
    const uint16_t* xr = Xb + (size_t)arow * 128 + kg * 8;
    s8v a0 = *(const s8v*)(xr);
    s8v a1 = *(const s8v*)(xr + 32);
    s8v a2 = *(const s8v*)(xr + 64);
    s8v a3 = *(const s8v*)(xr + 96);

    const int drow = row0 + kg * 4;

    for (int n0 = 0; n0 < N; n0 += 16) {
        const uint16_t* wl = WtL + (size_t)(n0 + ml) * 128 + kg * 8;
        const uint16_t* wr = WtR + (size_t)(n0 + ml) * 128 + kg * 8;
        f4v accL = {0.f, 0.f, 0.f, 0.f};
        f4v accR = {0.f, 0.f, 0.f, 0.f};
        accL = __builtin_amdgcn_mfma_f32_16x16x32_bf16(a0, *(const s8v*)(wl), accL, 0, 0, 0);
        accR = __builtin_amdgcn_mfma_f32_16x16x32_bf16(a0, *(const s8v*)(wr), accR, 0, 0, 0);
        accL = __builtin_amdgcn_mfma_f32_16x16x32_bf16(a1, *(const s8v*)(wl + 32), accL, 0, 0, 0);
        accR = __builtin_amdgcn_mfma_f32_16x16x32_bf16(a1, *(const s8v*)(wr + 32), accR, 0, 0, 0);
        accL = __builtin_amdgcn_mfma_f32_16x16x32_bf16(a2, *(const s8v*)(wl + 64), accL, 0, 0, 0);
        accR = __builtin_amdgcn_mfma_f32_16x16x32_bf16(a2, *(const s8v*)(wr + 64), accR, 0, 0, 0);
        accL = __builtin_amdgcn_mfma_f32_16x16x32_bf16(a3, *(const s8v*)(wl + 96), accL, 0, 0, 0);
        accR = __builtin_amdgcn_mfma_f32_16x16x32_bf16(a3, *(const s8v*)(wr + 96), accR, 0, 0, 0);

        float bv = bias[n0 + ml];
#pragma unroll
        for (int r = 0; r < 4; ++r) {
            int g = drow + r;
            if (g < M) {
                YL[(size_t)g * N + n0 + ml] = f2bf(accL[r]);
                ZB[(size_t)g * N + n0 + ml] = f2bf(accR[r] + bv);
            }
        }
    }
}

// ---------------- aggregation epilogues ----------------
// 2 nodes per wave; 32 lanes/node; lane owns 4 channels (uint2 = 4 bf16 = 8B load).
// mean + Z + relu + embedded-threefry dropout -> H bf16. (threefry overlaps gather
// latency via TLP — standalone mask kernel was measured SLOWER, round 11.)
__global__ __launch_bounds__(256) void agg128_kernel(
        const uint16_t* __restrict__ Yl, const uint16_t* __restrict__ Zb,
        const int* __restrict__ rowptr, const int* __restrict__ col,
        uint16_t* __restrict__ H, int n, uint32_t k0, uint32_t k1) {
    int wv = threadIdx.x >> 6, lane = threadIdx.x & 63;
    int half = lane >> 5, sl = lane & 31;
    int node = blockIdx.x * 8 + wv * 2 + half;
    if (node >= n) return;
    const uint2* ylp = (const uint2*)Yl;
    int beg = rowptr[node], end = rowptr[node + 1];
    float a0 = 0.f, a1 = 0.f, a2 = 0.f, a3 = 0.f;
    int e = beg;
    for (; e + 3 < end; e += 4) {
        int j0 = col[e], j1 = col[e + 1], j2 = col[e + 2], j3 = col[e + 3];
        uint2 v0 = ylp[(size_t)j0 * 32 + sl];
        uint2 v1 = ylp[(size_t)j1 * 32 + sl];
        uint2 v2 = ylp[(size_t)j2 * 32 + sl];
        uint2 v3 = ylp[(size_t)j3 * 32 + sl];
        a0 += bflo(v0.x) + bflo(v1.x) + bflo(v2.x) + bflo(v3.x);
        a1 += bfhi(v0.x) + bfhi(v1.x) + bfhi(v2.x) + bfhi(v3.x);
        a2 += bflo(v0.y) + bflo(v1.y) + bflo(v2.y) + bflo(v3.y);
        a3 += bfhi(v0.y) + bfhi(v1.y) + bfhi(v2.y) + bfhi(v3.y);
    }
    for (; e < end; ++e) {
        uint2 v = ylp[(size_t)col[e] * 32 + sl];
        a0 += bflo(v.x); a1 += bfhi(v.x);
        a2 += bflo(v.y); a3 += bfhi(v.y);
    }
    int cnt = end - beg;
    float inv = 1.0f / (float)(cnt > 1 ? cnt : 1);
    uint2 z = ((const uint2*)Zb)[(size_t)node * 32 + sl];
    float h0 = fmaxf(a0 * inv + bflo(z.x), 0.0f);
    float h1 = fmaxf(a1 * inv + bfhi(z.x), 0.0f);
    float h2 = fmaxf(a2 * inv + bflo(z.y), 0.0f);
    float h3 = fmaxf(a3 * inv + bfhi(z.y), 0.0f);
    uint32_t idx = (uint32_t)node * 128u + (uint32_t)sl * 4u;
    h0 = tf_keep(idx,      k0, k1) ? h0 * 2.0f : 0.0f;
    h1 = tf_keep(idx + 1u, k0, k1) ? h1 * 2.0f : 0.0f;
    h2 = tf_keep(idx + 2u, k0, k1) ? h2 * 2.0f : 0.0f;
    h3 = tf_keep(idx + 3u, k0, k1) ? h3 * 2.0f : 0.0f;
    uint2 o;
    o.x = (uint32_t)f2bf(h0) | ((uint32_t)f2bf(h1) << 16);
    o.y = (uint32_t)f2bf(h2) | ((uint32_t)f2bf(h3) << 16);
    ((uint2*)H)[(size_t)node * 32 + sl] = o;
}

// final layer: 2 nodes/wave, 32 lanes/node, lane owns 2 channels. mean + Z -> fp32 out.
__global__ __launch_bounds__(256) void agg64_kernel(
        const uint16_t* __restrict__ Yl, const uint16_t* __restrict__ Zb,
        const int* __restrict__ rowptr, const int* __restrict__ col,
        float* __restrict__ out, int n) {
    int wv = threadIdx.x >> 6, lane = threadIdx.x & 63;
    int half = lane >> 5, sl = lane & 31;
    int node = blockIdx.x * 8 + wv * 2 + half;
    if (node >= n) return;
    const uint32_t* ylp = (const uint32_t*)Yl;
    int beg = rowptr[node], end = rowptr[node + 1];
    float a0 = 0.f, a1 = 0.f;
    int e = beg;
    for (; e + 3 < end; e += 4) {
        int j0 = col[e], j1 = col[e + 1], j2 = col[e + 2], j3 = col[e + 3];
        uint32_t v0 = ylp[(size_t)j0 * 32 + sl];
        uint32_t v1 = ylp[(size_t)j1 * 32 + sl];
        uint32_t v2 = ylp[(size_t)j2 * 32 + sl];
        uint32_t v3 = ylp[(size_t)j3 * 32 + sl];
        a0 += bflo(v0) + bflo(v1) + bflo(v2) + bflo(v3);
        a1 += bfhi(v0) + bfhi(v1) + bfhi(v2) + bfhi(v3);
    }
    for (; e < end; ++e) {
        uint32_t v = ylp[(size_t)col[e] * 32 + sl];
        a0 += bflo(v); a1 += bfhi(v);
    }
    int cnt = end - beg;
    float inv = 1.0f / (float)(cnt > 1 ? cnt : 1);
    uint32_t z = ((const uint32_t*)Zb)[(size_t)node * 32 + sl];
    float2 o;
    o.x = a0 * inv + bflo(z);
    o.y = a1 * inv + bfhi(z);
    *(float2*)(out + (size_t)node * 64 + sl * 2) = o;
}

// ---------------- host ----------------
extern "C" void kernel_launch(void* const* d_in, const int* in_sizes, int n_in,
                              void* d_out, int out_size, void* d_ws, size_t ws_size,
                              hipStream_t stream) {
    const float* x   = (const float*)d_in[0];
    const int*   ei  = (const int*)d_in[1];
    const float* Wl0 = (const float*)d_in[2];
    const float* Wr0 = (const float*)d_in[3];
    const float* b0  = (const float*)d_in[4];
    const float* Wl1 = (const float*)d_in[5];
    const float* Wr1 = (const float*)d_in[6];
    const float* b1  = (const float*)d_in[7];
    const float* Wl2 = (const float*)d_in[8];
    const float* Wr2 = (const float*)d_in[9];
    const float* b2  = (const float*)d_in[10];

    const int N = in_sizes[0] / 128;     // 100000 (< 2^17, required by tmp packing)
    const int E = in_sizes[1] / 2;       // 1600000
    const int* srcp = ei;

    const int nA   = (E + ECHUNK - 1) / ECHUNK;   // 98
    const int NBUK = (N + 511) >> 9;              // 196 (<=256)
    const int L    = NBUK * nA;                   // ~19208 (<=1024*elpt)

    char* ws = (char*)d_ws;
    size_t off = 0;
    auto alloc = [&](size_t bytes) {
        size_t o = off;
        off = (off + bytes + 255) & ~(size_t)255;
        return o;
    };
    int*      rowptr = (int*)(ws + alloc((size_t)(N + 1) * 4));
    int*      hist   = (int*)(ws + alloc((size_t)L * 4));
    int*      bofs   = (int*)(ws + alloc((size_t)(L + 1) * 4));
    uint32_t* tmp    = (uint32_t*)(ws + alloc((size_t)E * 4));
    int*      col    = (int*)(ws + alloc((size_t)E * 4));
    uint16_t* Xb     = (uint16_t*)(ws + alloc((size_t)N * 128 * 2));
    uint16_t* Hb     = (uint16_t*)(ws + alloc((size_t)N * 128 * 2));
    uint16_t* Byl    = (uint16_t*)(ws + alloc((size_t)N * 128 * 2));
    uint16_t* Czb    = (uint16_t*)(ws + alloc((size_t)N * 128 * 2));
    uint16_t* Wt0l   = (uint16_t*)(ws + alloc(128 * 128 * 2));
    uint16_t* Wt0r   = (uint16_t*)(ws + alloc(128 * 128 * 2));
    uint16_t* Wt1l   = (uint16_t*)(ws + alloc(128 * 128 * 2));
    uint16_t* Wt1r   = (uint16_t*)(ws + alloc(128 * 128 * 2));
    uint16_t* Wt2l   = (uint16_t*)(ws + alloc(128 * 128 * 2));
    uint16_t* Wt2r   = (uint16_t*)(ws + alloc(128 * 128 * 2));

    // dropout keys: jax.random.split(jax.random.key(42), 2), partitionable scheme.
    uint32_t k00, k01, k10, k11;
    tf2x32(0u, 42u, 0u, 0u, k00, k01);   // dk[0]
    tf2x32(0u, 42u, 0u, 1u, k10, k11);   // dk[1]

    // ---- bucketed CSR build (4 dispatches) ----
    bucketcount_kernel<<<nA, 256, 0, stream>>>(srcp, hist, E, nA, NBUK);
    scanL_kernel<<<1, 1024, 0, stream>>>(hist, bofs, L);
    bucketscatter_kernel<<<nA, 256, 0, stream>>>(srcp, bofs, tmp, E, nA, NBUK);
    fusedcsr_kernel<<<NBUK, 512, 0, stream>>>(tmp, bofs, rowptr, col, nA, N, E);

    // ---- converts (1 dispatch) ----
    int nxb = N * 128 / 4 / 256;   // 12500 exact
    CPack cp;
    cp.wsrc[0] = Wl0; cp.wdst[0] = Wt0l; cp.wn[0] = 128;
    cp.wsrc[1] = Wr0; cp.wdst[1] = Wt0r; cp.wn[1] = 128;
    cp.wsrc[2] = Wl1; cp.wdst[2] = Wt1l; cp.wn[2] = 128;
    cp.wsrc[3] = Wr1; cp.wdst[3] = Wt1r; cp.wn[3] = 128;
    cp.wsrc[4] = Wl2; cp.wdst[4] = Wt2l; cp.wn[4] = 64;
    cp.wsrc[5] = Wr2; cp.wdst[5] = Wt2r; cp.wn[5] = 64;
    int acc = 0;
    for (int s = 0; s < 6; ++s) { cp.wboff[s] = acc; acc += cp.wn[s] * 128 / 256; }
    cp.wboff[6] = acc;
    conv_all_kernel<<<nxb + acc, 256, 0, stream>>>(x, Xb, nxb, cp);

    dim3 blk(256);
    dim3 gg((N + 63) / 64);
    dim3 gagg((N + 7) / 8);

    // ---- layer 0 ----
    pair_gemm_kernel<<<gg, blk, 0, stream>>>(Xb, Wt0l, Wt0r, b0, Byl, Czb, N, 128);
    agg128_kernel<<<gagg, blk, 0, stream>>>(Byl, Czb, rowptr, col, Hb, N, k00, k01);
    // ---- layer 1 ----
    pair_gemm_kernel<<<gg, blk, 0, stream>>>(Hb, Wt1l, Wt1r, b1, Byl, Czb, N, 128);
    agg128_kernel<<<gagg, blk, 0, stream>>>(Byl, Czb, rowptr, col, Hb, N, k10, k11);
    // ---- layer 2: project (128->64) then aggregate ----
    pair_gemm_kernel<<<gg, blk, 0, stream>>>(Hb, Wt2l, Wt2r, b2, Byl, Czb, N, 64);
    agg64_kernel<<<gagg, blk, 0, stream>>>(Byl, Czb, rowptr, col, (float*)d_out, N);
}